// Round 6
// baseline (283.995 us; speedup 1.0000x reference)
//
#include <hip/hip_runtime.h>
#include <math.h>

#define DN  768
#define NC  53
#define NCP 64         // classes padded for MFMA
#define BPB 16         // bags per block
#define RB  128        // rows per chunk (4 waves x 32)
#define NKS 24         // K steps of 32
#define YS  66         // yt row stride (floats)

typedef __attribute__((ext_vector_type(8))) __bf16 bf16x8;
typedef __attribute__((ext_vector_type(8))) short short8v;
typedef __attribute__((ext_vector_type(4))) float f32x4;

// f32 -> bf16 bits, round-to-nearest-even
static __device__ __forceinline__ unsigned short f2bf(float f) {
    unsigned int u = __builtin_bit_cast(unsigned int, f);
    u = (u + 0x7FFFu + ((u >> 16) & 1u)) >> 16;
    return (unsigned short)u;
}
static __device__ __forceinline__ float bf2f(unsigned short h) {
    unsigned int u = ((unsigned int)h) << 16;
    return __builtin_bit_cast(float, u);
}

// ---- k0: W -> Wh + Wl (bf16 split), zero-padded to 64 rows -----------------
__global__ void prep_w(const float* __restrict__ w,
                       unsigned short* __restrict__ wh,
                       unsigned short* __restrict__ wl) {
    int i = blockIdx.x * 256 + threadIdx.x;
    if (i >= NCP * DN) return;
    int row = i / DN;
    float v = (row < NC) ? w[i] : 0.f;
    unsigned short h = f2bf(v);
    wh[i] = h;
    wl[i] = f2bf(v - bf2f(h));
}

// ---- offs[b] = lower_bound(seg, b), b in [0, B] ----------------------------
__global__ void offs_kernel(const int* __restrict__ seg, int* __restrict__ offs,
                            int N, int B) {
    int i = blockIdx.x * blockDim.x + threadIdx.x;
    if (i >= N) return;
    int cur  = seg[i];
    int prev = (i == 0) ? -1 : seg[i - 1];
    for (int b = prev + 1; b <= cur; ++b) offs[b] = i;
    if (i == N - 1)
        for (int b = cur + 1; b <= B; ++b) offs[b] = N;
}

// ---- fused: direct-load MFMA -> Y-tile in LDS -> online softmax-pool --------
// Block owns 16 consecutive bags (contiguous rows). Chunk = 128 rows.
// Wave = 32 rows x 64 cols, A-frags straight from global (no x staging, no
// K-loop barriers). 2 barriers per chunk total.
__global__ __launch_bounds__(256, 4) void fused2(
    const float* __restrict__ x,
    const int*   __restrict__ label,
    const unsigned short* __restrict__ wh,
    const unsigned short* __restrict__ wl,
    const float* __restrict__ bias,
    const int*   __restrict__ offs,
    float*       __restrict__ out,
    int N, int Btot)
{
    __shared__ float yt[RB * YS];   // 33792 B
    __shared__ float se[4][64];

    const int tid  = threadIdx.x;
    const int lane = tid & 63;
    const int wv   = tid >> 6;
    const int r16  = lane & 15;
    const int kg   = lane >> 4;     // 0..3

    const int b0   = blockIdx.x * BPB;
    const int bEnd = (b0 + BPB < Btot) ? b0 + BPB : Btot;
    const int r0 = offs[b0];
    const int r1 = offs[bEnd];

    // wave wv owns bags b0 + wv*4 .. +4
    int sLo[4], sHi[4];
    float bm[4], bden[4], bfac[4];
    #pragma unroll
    for (int s = 0; s < 4; ++s) {
        const int bag = b0 + wv * 4 + s;
        sLo[s] = (bag < bEnd) ? offs[bag]     : 0;
        sHi[s] = (bag < bEnd) ? offs[bag + 1] : 0;
        bm[s] = -INFINITY; bden[s] = 0.f; bfac[s] = 0.f;
    }

    for (int cr = r0; cr < r1; cr += RB) {
        // ---- compute phase: no LDS, no barriers; 32 rows/wave x 64 cols ----
        f32x4 acc[2][4];
        #pragma unroll
        for (int f = 0; f < 2; ++f)
            #pragma unroll
            for (int ct = 0; ct < 4; ++ct)
                acc[f][ct] = (f32x4){0.f, 0.f, 0.f, 0.f};

        const long rA = (long)cr + wv * 32 + r16;
        #pragma unroll 2
        for (int ks = 0; ks < NKS; ++ks) {
            const int ko = ks * 32 + kg * 8;
            short8v a8[2];
            #pragma unroll
            for (int f = 0; f < 2; ++f) {
                long rg = rA + f * 16; if (rg > N - 1) rg = N - 1;   // tail clamp
                const float4 u0 = *(const float4*)(x + rg * DN + ko);
                const float4 u1 = *(const float4*)(x + rg * DN + ko + 4);
                short8v t;
                t[0] = (short)f2bf(u0.x); t[1] = (short)f2bf(u0.y);
                t[2] = (short)f2bf(u0.z); t[3] = (short)f2bf(u0.w);
                t[4] = (short)f2bf(u1.x); t[5] = (short)f2bf(u1.y);
                t[6] = (short)f2bf(u1.z); t[7] = (short)f2bf(u1.w);
                a8[f] = t;
            }
            #pragma unroll
            for (int ct = 0; ct < 4; ++ct) {
                const size_t wo = (size_t)(ct * 16 + r16) * DN + ko;
                const short8v bh = *(const short8v*)(wh + wo);
                const short8v bl = *(const short8v*)(wl + wo);
                #pragma unroll
                for (int f = 0; f < 2; ++f) {
                    acc[f][ct] = __builtin_amdgcn_mfma_f32_16x16x32_bf16(
                        __builtin_bit_cast(bf16x8, a8[f]), __builtin_bit_cast(bf16x8, bh),
                        acc[f][ct], 0, 0, 0);
                    acc[f][ct] = __builtin_amdgcn_mfma_f32_16x16x32_bf16(
                        __builtin_bit_cast(bf16x8, a8[f]), __builtin_bit_cast(bf16x8, bl),
                        acc[f][ct], 0, 0, 0);
                }
            }
        }

        __syncthreads();   // prev softmax phase done reading yt
        // C/D layout: col = r16, row-in-frag = kg*4 + r
        #pragma unroll
        for (int f = 0; f < 2; ++f)
            #pragma unroll
            for (int ct = 0; ct < 4; ++ct) {
                const int row = wv * 32 + f * 16 + kg * 4;
                #pragma unroll
                for (int r = 0; r < 4; ++r)
                    yt[(row + r) * YS + ct * 16 + r16] = acc[f][ct][r];
            }
        __syncthreads();   // yt ready

        // ---- softmax-pool phase: wave-local, no barriers ----
        #pragma unroll
        for (int s = 0; s < 4; ++s) {
            int lo = sLo[s] > cr ? sLo[s] : cr;
            int hi = sHi[s] < cr + RB ? sHi[s] : cr + RB;
            if (lo >= hi) continue;                       // wave-uniform
            for (int t0 = lo; t0 < hi; t0 += 64) {
                const int j = t0 + lane;
                float att = -INFINITY;
                if (j < hi) att = yt[(j - cr) * YS + label[j]];
                float cm = att;
                #pragma unroll
                for (int off = 1; off < 64; off <<= 1) cm = fmaxf(cm, __shfl_xor(cm, off));
                const float nm  = fmaxf(bm[s], cm);
                const float scv = __expf(bm[s] - nm);     // first update: exp(-inf)=0
                const float e   = (j < hi) ? __expf(att - nm) : 0.f;
                float cd = e;
                #pragma unroll
                for (int off = 1; off < 64; off <<= 1) cd += __shfl_xor(cd, off);
                bden[s] = bden[s] * scv + cd;
                se[wv][lane] = e;                          // same-wave LDS broadcast
                const int cnt = (hi - t0 < 64) ? hi - t0 : 64;
                float f0 = 0.f, f1 = 0.f, f2 = 0.f, f3 = 0.f;
                int t = 0;
                const int base = t0 - cr;
                for (; t + 4 <= cnt; t += 4) {             // 4 chains: breaks FMA dep
                    f0 += se[wv][t]     * yt[(base + t)     * YS + lane];
                    f1 += se[wv][t + 1] * yt[(base + t + 1) * YS + lane];
                    f2 += se[wv][t + 2] * yt[(base + t + 2) * YS + lane];
                    f3 += se[wv][t + 3] * yt[(base + t + 3) * YS + lane];
                }
                for (; t < cnt; ++t)
                    f0 += se[wv][t] * yt[(base + t) * YS + lane];
                bfac[s] = bfac[s] * scv + ((f0 + f1) + (f2 + f3));
                bm[s] = nm;
            }
        }
    }

    // ---- epilogue ----
    #pragma unroll
    for (int s = 0; s < 4; ++s) {
        const int bag = b0 + wv * 4 + s;
        if (bag < bEnd && lane < NC) {
            const float inv = (bden[s] == 0.f) ? 0.f : 1.f / bden[s];  // empty bag -> bias
            out[(size_t)bag * NC + lane] = bfac[s] * inv + bias[lane];
        }
    }
}

extern "C" void kernel_launch(void* const* d_in, const int* in_sizes, int n_in,
                              void* d_out, int out_size, void* d_ws, size_t ws_size,
                              hipStream_t stream)
{
    const float* x     = (const float*)d_in[0];
    const int*   label = (const int*)  d_in[1];
    const int*   seg   = (const int*)  d_in[2];
    const float* w     = (const float*)d_in[3];
    const float* bias  = (const float*)d_in[4];
    float*       out   = (float*)d_out;

    const int N = in_sizes[0] / DN;     // 131072
    const int B = out_size / NC;        // 16384

    unsigned short* wh   = (unsigned short*)d_ws;                    // 96 KB
    unsigned short* wl   = (unsigned short*)((char*)d_ws + 131072);  // 96 KB
    int*            offs = (int*)((char*)d_ws + 262144);             // 64 KB

    hipLaunchKernelGGL(prep_w, dim3((NCP * DN + 255) / 256), dim3(256), 0, stream,
                       w, wh, wl);
    hipLaunchKernelGGL(offs_kernel, dim3((N + 255) / 256), dim3(256), 0, stream,
                       seg, offs, N, B);
    hipLaunchKernelGGL(fused2, dim3((B + BPB - 1) / BPB), dim3(256), 0, stream,
                       x, label, wh, wl, bias, offs, out, N, B);
}

// Round 7
// 119.017 us; speedup vs baseline: 2.3862x; 2.3862x over previous
//
#include <hip/hip_runtime.h>
#include <math.h>

#define DN  768
#define NC  53
#define NCP 64         // classes padded for MFMA
#define NKS 24         // K steps of 32
#define MB  256        // rows per block (64/wave)

typedef __attribute__((ext_vector_type(8))) __bf16 bf16x8;
typedef __attribute__((ext_vector_type(8))) short short8v;
typedef __attribute__((ext_vector_type(4))) float f32x4;

// f32 -> bf16 bits, round-to-nearest-even
static __device__ __forceinline__ unsigned short f2bf(float f) {
    unsigned int u = __builtin_bit_cast(unsigned int, f);
    u = (u + 0x7FFFu + ((u >> 16) & 1u)) >> 16;
    return (unsigned short)u;
}

// ---- k0: W -> fragment-major bf16 wb[((ks*4+ct)*64+lane)*8+e] --------------
__global__ void prep_wb(const float* __restrict__ w, unsigned short* __restrict__ wb) {
    int i = blockIdx.x * 256 + threadIdx.x;       // NKS*4*64*8 = 49152
    if (i >= NKS * 4 * 64 * 8) return;
    const int e    = i & 7;
    const int lane = (i >> 3) & 63;
    const int ct   = (i >> 9) & 3;
    const int ks   = i >> 11;
    const int cls  = ct * 16 + (lane & 15);
    const int k    = ks * 32 + ((lane >> 4) << 3) + e;
    wb[i] = (cls < NC) ? f2bf(w[cls * DN + k]) : (unsigned short)0;
}

// ---- offs[b] = lower_bound(seg, b), b in [0, B] ----------------------------
__global__ void offs_kernel(const int* __restrict__ seg, int* __restrict__ offs,
                            int N, int B) {
    int i = blockIdx.x * blockDim.x + threadIdx.x;
    if (i >= N) return;
    int cur  = seg[i];
    int prev = (i == 0) ? -1 : seg[i - 1];
    for (int b = prev + 1; b <= cur; ++b) offs[b] = i;
    if (i == N - 1)
        for (int b = cur + 1; b <= B; ++b) offs[b] = N;
}

// ---- k1: Y[N][64] = bf16(X) @ bf16(W)^T; no LDS, no barriers ----------------
// wave = 64 rows x 64 cols; A + B loads register-double-buffered (T14).
#define ISSUE(buf, ks)                                                         \
    {                                                                          \
        _Pragma("unroll")                                                      \
        for (int f = 0; f < 4; ++f) {                                          \
            const float* ap = a0 + (size_t)f * 16 * DN + (ks) * 32;            \
            la[buf][f * 2]     = *(const float4*)(ap);                         \
            la[buf][f * 2 + 1] = *(const float4*)(ap + 4);                     \
        }                                                                      \
        _Pragma("unroll")                                                      \
        for (int ct = 0; ct < 4; ++ct)                                         \
            lb[buf][ct] = *(const short8v*)(wb + (((ks) * 4 + ct) * 64 + lane) * 8); \
    }

__global__ __launch_bounds__(256) void gemm_y2(
    const float* __restrict__ x,
    const unsigned short* __restrict__ wb,
    float* __restrict__ y)
{
    const int lane = threadIdx.x & 63;
    const int wv   = threadIdx.x >> 6;
    const int r16  = lane & 15;
    const int kg   = lane >> 4;
    const long row0 = (long)blockIdx.x * MB + wv * 64;

    f32x4 acc[4][4];
    #pragma unroll
    for (int f = 0; f < 4; ++f)
        #pragma unroll
        for (int ct = 0; ct < 4; ++ct)
            acc[f][ct] = (f32x4){0.f, 0.f, 0.f, 0.f};

    const float* a0 = x + (row0 + r16) * DN + kg * 8;

    float4  la[2][8];
    short8v lb[2][4];
    ISSUE(0, 0)

    #pragma unroll
    for (int ks = 0; ks < NKS; ++ks) {
        const int cur = ks & 1, nxt = cur ^ 1;
        if (ks + 1 < NKS) ISSUE(nxt, ks + 1)     // issue next batch BEFORE using cur

        short8v a8[4];
        #pragma unroll
        for (int f = 0; f < 4; ++f) {
            const float4 u0 = la[cur][f * 2], u1 = la[cur][f * 2 + 1];
            short8v t;
            t[0] = (short)f2bf(u0.x); t[1] = (short)f2bf(u0.y);
            t[2] = (short)f2bf(u0.z); t[3] = (short)f2bf(u0.w);
            t[4] = (short)f2bf(u1.x); t[5] = (short)f2bf(u1.y);
            t[6] = (short)f2bf(u1.z); t[7] = (short)f2bf(u1.w);
            a8[f] = t;
        }
        #pragma unroll
        for (int ct = 0; ct < 4; ++ct)
            #pragma unroll
            for (int f = 0; f < 4; ++f)
                acc[f][ct] = __builtin_amdgcn_mfma_f32_16x16x32_bf16(
                    __builtin_bit_cast(bf16x8, a8[f]),
                    __builtin_bit_cast(bf16x8, lb[cur][ct]), acc[f][ct], 0, 0, 0);
    }

    // C/D: col = r16 (class), row = kg*4 + r within each 16-row frag
    #pragma unroll
    for (int f = 0; f < 4; ++f)
        #pragma unroll
        for (int ct = 0; ct < 4; ++ct) {
            const long row = row0 + f * 16 + kg * 4;
            #pragma unroll
            for (int r = 0; r < 4; ++r)
                y[(row + r) * NCP + ct * 16 + r16] = acc[f][ct][r];
        }
}

// ---- k2: per-bag softmax pooling over Y, lane-parallel ---------------------
__global__ __launch_bounds__(256) void pool_kernel(
    const float* __restrict__ y,
    const int*   __restrict__ label,
    const int*   __restrict__ offs,
    const float* __restrict__ bias,
    float*       __restrict__ out,
    int Btot)
{
    __shared__ float s_e[4][64];
    const int wv   = threadIdx.x >> 6;
    const int lane = threadIdx.x & 63;
    const int bag  = blockIdx.x * 4 + wv;
    if (bag >= Btot) return;
    const int s = offs[bag], e = offs[bag + 1];

    float m = -INFINITY, den = 0.f, facc = 0.f;
    for (int j0 = s; j0 < e; j0 += 64) {
        const int j = j0 + lane;
        float a = -INFINITY;
        if (j < e) a = y[(size_t)j * NCP + label[j]];    // lane-parallel gather
        float cm = a;
        #pragma unroll
        for (int off = 1; off < 64; off <<= 1) cm = fmaxf(cm, __shfl_xor(cm, off));
        const float nm = fmaxf(m, cm);
        const float sc = __expf(m - nm);                 // first iter: exp(-inf)=0
        const float ej = __expf(a - nm);                 // invalid lanes -> 0
        float cd = ej;
        #pragma unroll
        for (int off = 1; off < 64; off <<= 1) cd += __shfl_xor(cd, off);
        den = den * sc + cd;
        s_e[wv][lane] = ej;                              // same-wave LDS broadcast
        const int cnt = min(64, e - j0);
        float f0 = 0.f, f1 = 0.f, f2 = 0.f, f3 = 0.f;
        int t = 0;
        for (; t + 4 <= cnt; t += 4) {                   // 4 chains break FMA dep
            f0 += s_e[wv][t]     * y[(size_t)(j0 + t)     * NCP + lane];
            f1 += s_e[wv][t + 1] * y[(size_t)(j0 + t + 1) * NCP + lane];
            f2 += s_e[wv][t + 2] * y[(size_t)(j0 + t + 2) * NCP + lane];
            f3 += s_e[wv][t + 3] * y[(size_t)(j0 + t + 3) * NCP + lane];
        }
        for (; t < cnt; ++t)
            f0 += s_e[wv][t] * y[(size_t)(j0 + t) * NCP + lane];
        facc = facc * sc + ((f0 + f1) + (f2 + f3));
        m = nm;
    }
    if (lane < NC) {
        const float inv = (den == 0.f) ? 0.f : 1.f / den;   // empty bag -> bias
        out[(size_t)bag * NC + lane] = facc * inv + bias[lane];
    }
}

extern "C" void kernel_launch(void* const* d_in, const int* in_sizes, int n_in,
                              void* d_out, int out_size, void* d_ws, size_t ws_size,
                              hipStream_t stream)
{
    const float* x     = (const float*)d_in[0];
    const int*   label = (const int*)  d_in[1];
    const int*   seg   = (const int*)  d_in[2];
    const float* w     = (const float*)d_in[3];
    const float* bias  = (const float*)d_in[4];
    float*       out   = (float*)d_out;

    const int N = in_sizes[0] / DN;     // 131072
    const int B = out_size / NC;        // 16384

    unsigned short* wb   = (unsigned short*)d_ws;                    //  96 KB
    int*            offs = (int*)((char*)d_ws + 131072);             //  64 KB
    float*          y    = (float*)((char*)d_ws + 1048576);          // 33.5 MB

    hipLaunchKernelGGL(prep_wb, dim3(192), dim3(256), 0, stream, w, wb);
    hipLaunchKernelGGL(offs_kernel, dim3((N + 255) / 256), dim3(256), 0, stream,
                       seg, offs, N, B);
    hipLaunchKernelGGL(gemm_y2, dim3(N / MB), dim3(256), 0, stream, x, wb, y);
    hipLaunchKernelGGL(pool_kernel, dim3((B + 3) / 4), dim3(256), 0, stream,
                       y, label, offs, bias, out, B);
}

// Round 8
// 113.470 us; speedup vs baseline: 2.5028x; 1.0489x over previous
//
#include <hip/hip_runtime.h>
#include <math.h>

#define DN  768
#define NC  53
#define NCP 64         // classes padded for MFMA
#define NKS 24         // K steps of 32
#define MB  256        // rows per block (64/wave)
#define YTS 66         // LDS yt row stride (floats): 2-way banks on write (free)

typedef __attribute__((ext_vector_type(8))) __bf16 bf16x8;
typedef __attribute__((ext_vector_type(8))) short short8v;
typedef __attribute__((ext_vector_type(4))) float f32x4;

// f32 -> bf16 bits, round-to-nearest-even
static __device__ __forceinline__ unsigned short f2bf(float f) {
    unsigned int u = __builtin_bit_cast(unsigned int, f);
    u = (u + 0x7FFFu + ((u >> 16) & 1u)) >> 16;
    return (unsigned short)u;
}
static __device__ __forceinline__ float bf2f(unsigned short h) {
    unsigned int u = ((unsigned int)h) << 16;
    return __builtin_bit_cast(float, u);
}

// ---- k0 (merged): blocks 0..191 -> wb fragment-major; 192.. -> offs ---------
__global__ void prep_kernel(const float* __restrict__ w,
                            const int*   __restrict__ seg,
                            unsigned short* __restrict__ wb,
                            int* __restrict__ offs,
                            int N, int B) {
    const int bid = blockIdx.x;
    if (bid < 192) {
        int i = bid * 256 + threadIdx.x;          // covers NKS*4*64*8 = 49152
        const int e    = i & 7;
        const int lane = (i >> 3) & 63;
        const int ct   = (i >> 9) & 3;
        const int ks   = i >> 11;
        const int cls  = ct * 16 + (lane & 15);
        const int k    = ks * 32 + ((lane >> 4) << 3) + e;
        wb[i] = (cls < NC) ? f2bf(w[cls * DN + k]) : (unsigned short)0;
    } else {
        int i = (bid - 192) * 256 + threadIdx.x;
        if (i >= N) return;
        int cur  = seg[i];
        int prev = (i == 0) ? -1 : seg[i - 1];
        for (int b = prev + 1; b <= cur; ++b) offs[b] = i;
        if (i == N - 1)
            for (int b = cur + 1; b <= B; ++b) offs[b] = N;
    }
}

// ---- k1: Y_bf16[N][64] = bf16(X) @ bf16(W)^T; also att[j] = Y[j][label[j]] --
// wave = 64 rows x 64 cols; A + B loads register-double-buffered; no barriers.
#define ISSUE(buf, ks)                                                         \
    {                                                                          \
        _Pragma("unroll")                                                      \
        for (int f = 0; f < 4; ++f) {                                          \
            const float* ap = a0 + (size_t)f * 16 * DN + (ks) * 32;            \
            la[buf][f * 2]     = *(const float4*)(ap);                         \
            la[buf][f * 2 + 1] = *(const float4*)(ap + 4);                     \
        }                                                                      \
        _Pragma("unroll")                                                      \
        for (int ct = 0; ct < 4; ++ct)                                         \
            lb[buf][ct] = *(const short8v*)(wb + (((ks) * 4 + ct) * 64 + lane) * 8); \
    }

__global__ __launch_bounds__(256) void gemm_y3(
    const float* __restrict__ x,
    const int*   __restrict__ label,
    const unsigned short* __restrict__ wb,
    unsigned short* __restrict__ yb,   // [N][64] bf16
    float* __restrict__ att)           // [N]
{
    __shared__ float yt[4][64 * YTS];  // 67.6 KB, one 64x64 tile per wave

    const int lane = threadIdx.x & 63;
    const int wv   = threadIdx.x >> 6;
    const int r16  = lane & 15;
    const int kg   = lane >> 4;
    const long row0 = (long)blockIdx.x * MB + wv * 64;

    f32x4 acc[4][4];
    #pragma unroll
    for (int f = 0; f < 4; ++f)
        #pragma unroll
        for (int ct = 0; ct < 4; ++ct)
            acc[f][ct] = (f32x4){0.f, 0.f, 0.f, 0.f};

    const float* a0 = x + (row0 + r16) * DN + kg * 8;

    float4  la[2][8];
    short8v lb[2][4];
    ISSUE(0, 0)

    #pragma unroll
    for (int ks = 0; ks < NKS; ++ks) {
        const int cur = ks & 1, nxt = cur ^ 1;
        if (ks + 1 < NKS) ISSUE(nxt, ks + 1)     // issue next batch BEFORE using cur

        short8v a8[4];
        #pragma unroll
        for (int f = 0; f < 4; ++f) {
            const float4 u0 = la[cur][f * 2], u1 = la[cur][f * 2 + 1];
            short8v t;
            t[0] = (short)f2bf(u0.x); t[1] = (short)f2bf(u0.y);
            t[2] = (short)f2bf(u0.z); t[3] = (short)f2bf(u0.w);
            t[4] = (short)f2bf(u1.x); t[5] = (short)f2bf(u1.y);
            t[6] = (short)f2bf(u1.z); t[7] = (short)f2bf(u1.w);
            a8[f] = t;
        }
        #pragma unroll
        for (int ct = 0; ct < 4; ++ct)
            #pragma unroll
            for (int f = 0; f < 4; ++f)
                acc[f][ct] = __builtin_amdgcn_mfma_f32_16x16x32_bf16(
                    __builtin_bit_cast(bf16x8, a8[f]),
                    __builtin_bit_cast(bf16x8, lb[cur][ct]), acc[f][ct], 0, 0, 0);
    }

    // Epilogue. C/D: col = r16 + ct*16 (class), row = f*16 + kg*4 + r.
    // (a) y -> global bf16, (b) tile -> wave-private LDS, (c) att gather.
    float* myt = yt[wv];
    #pragma unroll
    for (int f = 0; f < 4; ++f)
        #pragma unroll
        for (int ct = 0; ct < 4; ++ct) {
            const int rl = f * 16 + kg * 4;
            #pragma unroll
            for (int r = 0; r < 4; ++r) {
                const float v = acc[f][ct][r];
                myt[(rl + r) * YTS + ct * 16 + r16] = v;
                yb[(row0 + rl + r) * NCP + ct * 16 + r16] = f2bf(v);
            }
        }
    // same-wave LDS RAW: compiler inserts lgkmcnt wait; no barrier needed
    {
        const long grow = row0 + lane;            // lane <-> local row
        const int  lab  = label[grow];            // coalesced
        att[grow] = myt[lane * YTS + lab];        // LDS gather
    }
}

// ---- k2: per-bag softmax pooling: att coalesced + bf16 y rows ---------------
__global__ __launch_bounds__(256) void pool_kernel(
    const unsigned short* __restrict__ yb,
    const float* __restrict__ att,
    const int*   __restrict__ offs,
    const float* __restrict__ bias,
    float*       __restrict__ out,
    int Btot)
{
    __shared__ float s_e[4][64];
    const int wv   = threadIdx.x >> 6;
    const int lane = threadIdx.x & 63;
    const int bag  = blockIdx.x * 4 + wv;
    if (bag >= Btot) return;
    const int s = offs[bag], e = offs[bag + 1];

    float m = -INFINITY, den = 0.f, facc = 0.f;
    for (int j0 = s; j0 < e; j0 += 64) {
        const int j = j0 + lane;
        float a = (j < e) ? att[j] : -INFINITY;          // coalesced stream
        float cm = a;
        #pragma unroll
        for (int off = 1; off < 64; off <<= 1) cm = fmaxf(cm, __shfl_xor(cm, off));
        const float nm = fmaxf(m, cm);
        const float sc = __expf(m - nm);                 // first iter: exp(-inf)=0
        const float ej = (j < e) ? __expf(a - nm) : 0.f;
        float cd = ej;
        #pragma unroll
        for (int off = 1; off < 64; off <<= 1) cd += __shfl_xor(cd, off);
        den = den * sc + cd;
        s_e[wv][lane] = ej;                              // same-wave LDS broadcast
        const int cnt = min(64, e - j0);
        float f0 = 0.f, f1 = 0.f, f2 = 0.f, f3 = 0.f;
        int t = 0;
        for (; t + 4 <= cnt; t += 4) {                   // 4 chains break FMA dep
            f0 += s_e[wv][t]     * bf2f(yb[(size_t)(j0 + t)     * NCP + lane]);
            f1 += s_e[wv][t + 1] * bf2f(yb[(size_t)(j0 + t + 1) * NCP + lane]);
            f2 += s_e[wv][t + 2] * bf2f(yb[(size_t)(j0 + t + 2) * NCP + lane]);
            f3 += s_e[wv][t + 3] * bf2f(yb[(size_t)(j0 + t + 3) * NCP + lane]);
        }
        for (; t < cnt; ++t)
            f0 += s_e[wv][t] * bf2f(yb[(size_t)(j0 + t) * NCP + lane]);
        facc = facc * sc + ((f0 + f1) + (f2 + f3));
        m = nm;
    }
    if (lane < NC) {
        const float inv = (den == 0.f) ? 0.f : 1.f / den;   // empty bag -> bias
        out[(size_t)bag * NC + lane] = facc * inv + bias[lane];
    }
}

extern "C" void kernel_launch(void* const* d_in, const int* in_sizes, int n_in,
                              void* d_out, int out_size, void* d_ws, size_t ws_size,
                              hipStream_t stream)
{
    const float* x     = (const float*)d_in[0];
    const int*   label = (const int*)  d_in[1];
    const int*   seg   = (const int*)  d_in[2];
    const float* w     = (const float*)d_in[3];
    const float* bias  = (const float*)d_in[4];
    float*       out   = (float*)d_out;

    const int N = in_sizes[0] / DN;     // 131072
    const int B = out_size / NC;        // 16384

    unsigned short* wb   = (unsigned short*)d_ws;                    //  96 KB @ 0
    int*            offs = (int*)((char*)d_ws + 131072);             //  64 KB
    float*          att  = (float*)((char*)d_ws + 1048576);          // 512 KB
    unsigned short* yb   = (unsigned short*)((char*)d_ws + 2097152); // 16.8 MB

    hipLaunchKernelGGL(prep_kernel, dim3(192 + (N + 255) / 256), dim3(256), 0, stream,
                       w, seg, wb, offs, N, B);
    hipLaunchKernelGGL(gemm_y3, dim3(N / MB), dim3(256), 0, stream,
                       x, label, wb, yb, att);
    hipLaunchKernelGGL(pool_kernel, dim3((B + 3) / 4), dim3(256), 0, stream,
                       yb, att, offs, bias, out, B);
}